// Round 11
// baseline (84.058 us; speedup 1.0000x reference)
//
#include <hip/hip_runtime.h>
#include <math.h>

#define Q 64
#define NPB 256

typedef __attribute__((ext_vector_type(8))) short bf16x8;
typedef __attribute__((ext_vector_type(16))) float f32x16;
typedef __attribute__((ext_vector_type(4))) unsigned int u32x4;

union BFr { u32x4 u; bf16x8 v; };

#define MFMA32(a, b, cc) __builtin_amdgcn_mfma_f32_32x32x16_bf16(a, b, cc, 0, 0, 0)

// Continued-fraction Pade tanh: x(10395+1260t+21t^2)/(10395+4725t+210t^2+t^3),
// t=x^2, input clamped to |x|<=4.4. Max abs err ~7e-4 (<< bf16 act rounding).
__device__ __forceinline__ float pade_tanh(float x) {
    float xc = fminf(fmaxf(x, -4.4f), 4.4f);
    float t  = xc * xc;
    float p  = fmaf(t, fmaf(t, 21.0f, 1260.0f), 10395.0f);
    float q  = fmaf(t, fmaf(t, t + 210.0f, 4725.0f), 10395.0f);
    return (xc * p) * __builtin_amdgcn_rcpf(q);
}

__device__ __forceinline__ unsigned short bf16rne(float x) {
    unsigned u = __float_as_uint(x);
    return (unsigned short)((u + 0x7fffu + ((u >> 16) & 1u)) >> 16);
}

__device__ __forceinline__ void bf16split(float x, unsigned short& h, unsigned short& l) {
    h = bf16rne(x);
    float rest = x - __uint_as_float(((unsigned)h) << 16);
    l = bf16rne(rest);
}

// Packed f32->bf16 RNE: dst = {bf16(lo) in [15:0], bf16(hi) in [31:16]}
__device__ __forceinline__ unsigned cvt_pk_bf16(float lo, float hi) {
    unsigned r;
    asm("v_cvt_pk_bf16_f32 %0, %1, %2" : "=v"(r) : "v"(lo), "v"(hi));
    return r;
}

// Sum over each aligned 16-lane group, pure DPP (no LDS pipe).
// quad_perm xor1, xor2 -> quad sums; row_ror:4 + row_ror:8 -> full 16-row sum.
__device__ __forceinline__ float sum16_dpp(float x) {
    x += __int_as_float(__builtin_amdgcn_update_dpp(0, __float_as_int(x), 0xB1,  0xF, 0xF, true));
    x += __int_as_float(__builtin_amdgcn_update_dpp(0, __float_as_int(x), 0x4E,  0xF, 0xF, true));
    x += __int_as_float(__builtin_amdgcn_update_dpp(0, __float_as_int(x), 0x124, 0xF, 0xF, true));
    x += __int_as_float(__builtin_amdgcn_update_dpp(0, __float_as_int(x), 0x128, 0xF, 0xF, true));
    return x;
}

// Pre-split weights into 32x32x16 MFMA A-fragment order (hi + lo planes).
// A-frag layout: lane (c5=lane&31, h=lane>>5): row=32*mtp+c5, k=16*s+8*h+i.
// ws layout (unsigned short units):
//   [0)      WAH[L][mtp][s][lane][8]   3*2*4*64*8 = 12288
//   [12288)  WAL  same
//   [24576)  L0H[mtp][lane][8]         2*64*8 = 1024  (W0 cols k=0..2, bias col 3, 0 pad)
//   [25600)  L0L  same
__global__ __launch_bounds__(256)
void build_wfrag(const float* __restrict__ W0, const float* __restrict__ b0,
                 const float* __restrict__ W1, const float* __restrict__ W2,
                 const float* __restrict__ W3, unsigned short* __restrict__ ws)
{
    int idx = blockIdx.x * 256 + threadIdx.x;
    if (idx < 1536) {
        int L = idx >> 9, rem = idx & 511;
        int mtp = rem >> 8, s = (rem >> 6) & 3, lane = rem & 63;
        const float* W = (L == 0) ? W1 : (L == 1) ? W2 : W3;
        int n = 32 * mtp + (lane & 31);
        int hh2 = lane >> 5;
        #pragma unroll
        for (int i = 0; i < 8; ++i) {
            int k = 16 * s + 8 * hh2 + i;
            unsigned short hh, ll;
            bf16split(W[n * 64 + k], hh, ll);
            ws[idx * 8 + i] = hh;
            ws[12288 + idx * 8 + i] = ll;
        }
    } else if (idx < 1664) {
        int j = idx - 1536;
        int mtp = j >> 6, lane = j & 63;
        int n = 32 * mtp + (lane & 31);
        int hh2 = lane >> 5;
        #pragma unroll
        for (int i = 0; i < 8; ++i) {
            int k = 8 * hh2 + i;
            float v = (k < 3) ? W0[n * 3 + k] : ((k == 3) ? b0[n] : 0.0f);
            unsigned short hh, ll;
            bf16split(v, hh, ll);
            ws[24576 + j * 8 + i] = hh;
            ws[25600 + j * 8 + i] = ll;
        }
    }
}

// Build next-layer B-fragments from packed D-values via v_permlane32_swap.
#define BUILD_FRAGS(fr)                                               \
    BFr fr[4][2];                                                     \
    _Pragma("unroll")                                                 \
    for (int nt = 0; nt < 2; ++nt) {                                  \
        _Pragma("unroll")                                             \
        for (int s = 0; s < 4; ++s) {                                 \
            const int mt = s >> 1, e = 4 * (s & 1);                   \
            unsigned x1 = pk[mt][nt][e + 0], y1 = pk[mt][nt][e + 2];  \
            unsigned x2 = pk[mt][nt][e + 1], y2 = pk[mt][nt][e + 3];  \
            asm("v_permlane32_swap_b32 %0, %1" : "+v"(x1), "+v"(y1)); \
            asm("v_permlane32_swap_b32 %0, %1" : "+v"(x2), "+v"(y2)); \
            fr[s][nt].u = (u32x4){x1, x2, y1, y2};                    \
        }                                                             \
    }

__global__ __launch_bounds__(NPB, 4)
void bgk_mfma(const float* __restrict__ f,
              const float* __restrict__ macro,
              const float* __restrict__ pos,
              const float* __restrict__ b1,
              const float* __restrict__ b2,
              const float* __restrict__ b3,
              const float* __restrict__ W4,
              const float* __restrict__ b4,
              const unsigned short* __restrict__ ws,
              float* __restrict__ out, int n_nodes)
{
    __shared__ float4 s_prm[NPB];   // per-node {1/tau, lam, mu0, r}

    const int tid = threadIdx.x;
    const int wv = tid >> 6, lane = tid & 63;
    const int c5 = lane & 31, h = lane >> 5;
    const int nbase = blockIdx.x * NPB;
    const float XI_H = 70.0f / 63.0f;

    // ---- T14: issue phase-2 batch-0 f-loads NOW; HBM latency hides under MLP ----
    const int sub = lane >> 4;
    const int qi = (lane & 15) * 4;
    const int wbase = nbase + (wv << 6);
    float4 pre[8];
    #pragma unroll
    for (int k = 0; k < 8; ++k) {
        int n = wbase + k * 4 + sub;
        int ncl = (n < n_nodes) ? n : (n_nodes - 1);
        pre[k] = *(const float4*)(f + (size_t)ncl * Q + qi);
    }

    // ---- prolog: analytic lambda/mu0/r per node (thread t <-> node nbase+t) ----
    float lam, mu0, rgeo;
    {
        int n1 = nbase + tid;
        int nc2 = (n1 < n_nodes) ? n1 : (n_nodes - 1);
        float m0 = macro[nc2 * 2];
        rgeo = fmaxf(m0 / (m0 + XI_H), 1e-30f);
        float lr = logf(rgeo);
        lam = lr / XI_H;
        float r64 = __expf(64.0f * lr);
        mu0 = -logf((1.0f - r64) / (1.0f - rgeo));
    }

    const bf16x8* wAh = (const bf16x8*)(ws);
    const bf16x8* wAl = (const bf16x8*)(ws + 12288);
    const bf16x8* l0h = (const bf16x8*)(ws + 24576);
    const bf16x8* l0l = (const bf16x8*)(ws + 25600);
    const f32x16 zero16 = {0,0,0,0,0,0,0,0,0,0,0,0,0,0,0,0};

    unsigned pk[2][2][8];

    // ---- layer 0 (3->64), K=16, bias folded as input row k=3 of 1.0 ----
    {
        BFr bh[2], bl[2];
        #pragma unroll
        for (int nt = 0; nt < 2; ++nt) {
            int node = nbase + (wv << 6) + 32 * nt + c5;
            if (node >= n_nodes) node = n_nodes - 1;
            float m0 = macro[node * 2], m1 = macro[node * 2 + 1], pp = pos[node];
            unsigned short h0, l0_, h1, l1_, h2, l2_;
            bf16split(m0, h0, l0_); bf16split(m1, h1, l1_); bf16split(pp, h2, l2_);
            unsigned w0h = (unsigned)h0 | ((unsigned)h1 << 16);
            unsigned w1h = (unsigned)h2 | (0x3F80u << 16);
            unsigned w0l = (unsigned)l0_ | ((unsigned)l1_ << 16);
            unsigned w1l = (unsigned)l2_;
            bh[nt].u = (u32x4){ h ? 0u : w0h, h ? 0u : w1h, 0u, 0u };
            bl[nt].u = (u32x4){ h ? 0u : w0l, h ? 0u : w1l, 0u, 0u };
        }
        #pragma unroll
        for (int mtp = 0; mtp < 2; ++mtp) {
            bf16x8 Ah = l0h[mtp * 64 + lane];
            bf16x8 Al = l0l[mtp * 64 + lane];
            #pragma unroll
            for (int nt = 0; nt < 2; ++nt) {
                f32x16 t = zero16;
                t = MFMA32(Ah, bh[nt].v, t);
                t = MFMA32(Al, bh[nt].v, t);
                t = MFMA32(Ah, bl[nt].v, t);
                #pragma unroll
                for (int p = 0; p < 8; ++p)
                    pk[mtp][nt][p] = cvt_pk_bf16(pade_tanh(t[2 * p]), pade_tanh(t[2 * p + 1]));
            }
        }
    }

    // ---- hidden layers 1,2 (64->64): bias folded into MFMA C-init ----
#define HIDDEN(Lc, BIAS)                                                       \
    {                                                                          \
        BUILD_FRAGS(fr)                                                        \
        _Pragma("unroll")                                                      \
        for (int mtp = 0; mtp < 2; ++mtp) {                                    \
            f32x16 a0;                                                         \
            _Pragma("unroll")                                                  \
            for (int j = 0; j < 4; ++j) {                                      \
                float4 bv = *(const float4*)&(BIAS)[32 * mtp + 8 * j + 4 * h]; \
                a0[4 * j + 0] = bv.x; a0[4 * j + 1] = bv.y;                    \
                a0[4 * j + 2] = bv.z; a0[4 * j + 3] = bv.w;                    \
            }                                                                  \
            f32x16 a1 = a0;                                                    \
            _Pragma("unroll")                                                  \
            for (int s = 0; s < 4; ++s) {                                      \
                const int fo = (((Lc) * 2 + mtp) * 4 + s) * 64 + lane;         \
                bf16x8 Ah = wAh[fo], Al = wAl[fo];                             \
                a0 = MFMA32(Ah, fr[s][0].v, a0);                               \
                a0 = MFMA32(Al, fr[s][0].v, a0);                               \
                a1 = MFMA32(Ah, fr[s][1].v, a1);                               \
                a1 = MFMA32(Al, fr[s][1].v, a1);                               \
            }                                                                  \
            _Pragma("unroll")                                                  \
            for (int j = 0; j < 4; ++j) {                                      \
                float v0 = pade_tanh(a0[4 * j + 0]);                           \
                float v1 = pade_tanh(a0[4 * j + 1]);                           \
                float v2 = pade_tanh(a0[4 * j + 2]);                           \
                float v3 = pade_tanh(a0[4 * j + 3]);                           \
                pk[mtp][0][2 * j + 0] = cvt_pk_bf16(v0, v1);                   \
                pk[mtp][0][2 * j + 1] = cvt_pk_bf16(v2, v3);                   \
                float u0 = pade_tanh(a1[4 * j + 0]);                           \
                float u1 = pade_tanh(a1[4 * j + 1]);                           \
                float u2 = pade_tanh(a1[4 * j + 2]);                           \
                float u3 = pade_tanh(a1[4 * j + 3]);                           \
                pk[mtp][1][2 * j + 0] = cvt_pk_bf16(u0, u1);                   \
                pk[mtp][1][2 * j + 1] = cvt_pk_bf16(u2, u3);                   \
            }                                                                  \
        }                                                                      \
    }

    HIDDEN(0, b1)
    HIDDEN(1, b2)

    // ---- layer 3 + head (64->64->1): bias folded into C-init, fold W4 ----
    {
        BUILD_FRAGS(fr)
        float zp0 = 0.f, zp1 = 0.f;
        #pragma unroll
        for (int mtp = 0; mtp < 2; ++mtp) {
            f32x16 a0;
            #pragma unroll
            for (int j = 0; j < 4; ++j) {
                float4 bv = *(const float4*)&b3[32 * mtp + 8 * j + 4 * h];
                a0[4 * j + 0] = bv.x; a0[4 * j + 1] = bv.y;
                a0[4 * j + 2] = bv.z; a0[4 * j + 3] = bv.w;
            }
            f32x16 a1 = a0;
            #pragma unroll
            for (int s = 0; s < 4; ++s) {
                const int fo = ((2 * 2 + mtp) * 4 + s) * 64 + lane;
                bf16x8 Ah = wAh[fo], Al = wAl[fo];
                a0 = MFMA32(Ah, fr[s][0].v, a0);
                a0 = MFMA32(Al, fr[s][0].v, a0);
                a1 = MFMA32(Ah, fr[s][1].v, a1);
                a1 = MFMA32(Al, fr[s][1].v, a1);
            }
            #pragma unroll
            for (int j = 0; j < 4; ++j) {
                float4 w4v = *(const float4*)&W4[32 * mtp + 8 * j + 4 * h];
                zp0 = fmaf(w4v.x, pade_tanh(a0[4 * j + 0]), zp0);
                zp0 = fmaf(w4v.y, pade_tanh(a0[4 * j + 1]), zp0);
                zp0 = fmaf(w4v.z, pade_tanh(a0[4 * j + 2]), zp0);
                zp0 = fmaf(w4v.w, pade_tanh(a0[4 * j + 3]), zp0);
                zp1 = fmaf(w4v.x, pade_tanh(a1[4 * j + 0]), zp1);
                zp1 = fmaf(w4v.y, pade_tanh(a1[4 * j + 1]), zp1);
                zp1 = fmaf(w4v.z, pade_tanh(a1[4 * j + 2]), zp1);
                zp1 = fmaf(w4v.w, pade_tanh(a1[4 * j + 3]), zp1);
            }
        }
        const float b4s = b4[0];
        zp0 += __shfl_xor(zp0, 32, 64);
        zp1 += __shfl_xor(zp1, 32, 64);
        // After xor32 every lane holds both head sums; pick own node's in-register.
        float it0 = __expf(-(zp0 + b4s));
        float it1 = __expf(-(zp1 + b4s));
        float it  = h ? it1 : it0;
        // One ds_write_b128 per thread; consumed only by the same wave (no barrier).
        s_prm[tid] = (float4){ it, lam, mu0, rgeo };
    }

    // ---- Phase 2: batch 0 preloaded; DPP reduce; 1 ds_read_b128 for params ----
    const float x0 = (float)qi * XI_H;
    {
        float4 fr2[8];
        #pragma unroll
        for (int k = 0; k < 8; ++k) {
            int n = wbase + (8 + k) * 4 + sub;
            int ncl = (n < n_nodes) ? n : (n_nodes - 1);
            fr2[k] = *(const float4*)(f + (size_t)ncl * Q + qi);
        }
        #pragma unroll
        for (int kb = 0; kb < 2; ++kb) {
            #pragma unroll
            for (int k = 0; k < 8; ++k) {
                const int local = (kb * 8 + k) * 4 + sub;
                const int n = wbase + local;
                const float4 fv = kb ? fr2[k] : pre[k];

                const float s = sum16_dpp(fv.x + fv.y + fv.z + fv.w);
                const float rho = s * (1.0f / 64.0f);

                const float4 prm = s_prm[(wv << 6) + local];   // {it, lam, mu0, r}

                const float e0 = rho * __expf(fmaf(prm.y, x0, prm.z));
                const float e1 = e0 * prm.w;
                const float e2 = e1 * prm.w;
                const float e3 = e2 * prm.w;

                float4 o;
                o.x = (e0 - fv.x) * prm.x;
                o.y = (e1 - fv.y) * prm.x;
                o.z = (e2 - fv.z) * prm.x;
                o.w = (e3 - fv.w) * prm.x;

                if (n < n_nodes) *(float4*)(out + (size_t)n * Q + qi) = o;
            }
        }
    }
}

extern "C" void kernel_launch(void* const* d_in, const int* in_sizes, int n_in,
                              void* d_out, int out_size, void* d_ws, size_t ws_size,
                              hipStream_t stream) {
    const float* f     = (const float*)d_in[0];
    const float* macro = (const float*)d_in[1];
    const float* pos   = (const float*)d_in[2];
    const float* W0 = (const float*)d_in[3];  const float* b0 = (const float*)d_in[4];
    const float* W1 = (const float*)d_in[5];  const float* b1 = (const float*)d_in[6];
    const float* W2 = (const float*)d_in[7];  const float* b2 = (const float*)d_in[8];
    const float* W3 = (const float*)d_in[9];  const float* b3 = (const float*)d_in[10];
    const float* W4 = (const float*)d_in[11]; const float* b4 = (const float*)d_in[12];
    float* out = (float*)d_out;
    unsigned short* ws = (unsigned short*)d_ws;   // 53,248 B used

    const int n_nodes = in_sizes[0] / Q;   // 500000
    build_wfrag<<<7, 256, 0, stream>>>(W0, b0, W1, W2, W3, ws);

    const int blocks = (n_nodes + NPB - 1) / NPB;
    bgk_mfma<<<blocks, NPB, 0, stream>>>(f, macro, pos,
                                         b1, b2, b3, W4, b4, ws,
                                         out, n_nodes);
}

// Round 12
// 79.560 us; speedup vs baseline: 1.0565x; 1.0565x over previous
//
#include <hip/hip_runtime.h>
#include <math.h>

#define Q 64
#define NPB 64   // single-wave workgroups: dispatcher staggers phases across waves

typedef __attribute__((ext_vector_type(8))) short bf16x8;
typedef __attribute__((ext_vector_type(16))) float f32x16;
typedef __attribute__((ext_vector_type(4))) unsigned int u32x4;

union BFr { u32x4 u; bf16x8 v; };

#define MFMA32(a, b, cc) __builtin_amdgcn_mfma_f32_32x32x16_bf16(a, b, cc, 0, 0, 0)

// Paired continued-fraction Pade tanh: one v_rcp serves two activations.
// tanh(x) ~ x(10395+1260t+21t^2)/(10395+4725t+210t^2+t^3), t=x^2, |x|<=4.4.
// Max abs err ~7e-4 (<< bf16 activation rounding). q <= ~2e5 so q0*q1 safe.
__device__ __forceinline__ void pade_tanh2(float x0, float x1, float& y0, float& y1) {
    float c0 = fminf(fmaxf(x0, -4.4f), 4.4f);
    float c1 = fminf(fmaxf(x1, -4.4f), 4.4f);
    float t0 = c0 * c0, t1 = c1 * c1;
    float p0 = fmaf(t0, fmaf(t0, 21.0f, 1260.0f), 10395.0f);
    float p1 = fmaf(t1, fmaf(t1, 21.0f, 1260.0f), 10395.0f);
    float q0 = fmaf(t0, fmaf(t0, t0 + 210.0f, 4725.0f), 10395.0f);
    float q1 = fmaf(t1, fmaf(t1, t1 + 210.0f, 4725.0f), 10395.0f);
    float rq = __builtin_amdgcn_rcpf(q0 * q1);
    y0 = (c0 * p0) * (rq * q1);
    y1 = (c1 * p1) * (rq * q0);
}

__device__ __forceinline__ unsigned short bf16rne(float x) {
    unsigned u = __float_as_uint(x);
    return (unsigned short)((u + 0x7fffu + ((u >> 16) & 1u)) >> 16);
}

__device__ __forceinline__ void bf16split(float x, unsigned short& h, unsigned short& l) {
    h = bf16rne(x);
    float rest = x - __uint_as_float(((unsigned)h) << 16);
    l = bf16rne(rest);
}

// Packed f32->bf16 RNE: dst = {bf16(lo) in [15:0], bf16(hi) in [31:16]}
__device__ __forceinline__ unsigned cvt_pk_bf16(float lo, float hi) {
    unsigned r;
    asm("v_cvt_pk_bf16_f32 %0, %1, %2" : "=v"(r) : "v"(lo), "v"(hi));
    return r;
}

// Sum over each aligned 16-lane group, pure DPP (no LDS pipe).
__device__ __forceinline__ float sum16_dpp(float x) {
    x += __int_as_float(__builtin_amdgcn_update_dpp(0, __float_as_int(x), 0xB1,  0xF, 0xF, true));
    x += __int_as_float(__builtin_amdgcn_update_dpp(0, __float_as_int(x), 0x4E,  0xF, 0xF, true));
    x += __int_as_float(__builtin_amdgcn_update_dpp(0, __float_as_int(x), 0x124, 0xF, 0xF, true));
    x += __int_as_float(__builtin_amdgcn_update_dpp(0, __float_as_int(x), 0x128, 0xF, 0xF, true));
    return x;
}

// Pre-split weights into 32x32x16 MFMA A-fragment order (hi + lo planes).
// A-frag layout: lane (c5=lane&31, h=lane>>5): row=32*mtp+c5, k=16*s+8*h+i.
// ws layout (unsigned short units):
//   [0)      WAH[L][mtp][s][lane][8]   3*2*4*64*8 = 12288
//   [12288)  WAL  same
//   [24576)  L0H[mtp][lane][8]         2*64*8 = 1024  (W0 cols k=0..2, bias col 3, 0 pad)
//   [25600)  L0L  same
__global__ __launch_bounds__(256)
void build_wfrag(const float* __restrict__ W0, const float* __restrict__ b0,
                 const float* __restrict__ W1, const float* __restrict__ W2,
                 const float* __restrict__ W3, unsigned short* __restrict__ ws)
{
    int idx = blockIdx.x * 256 + threadIdx.x;
    if (idx < 1536) {
        int L = idx >> 9, rem = idx & 511;
        int mtp = rem >> 8, s = (rem >> 6) & 3, lane = rem & 63;
        const float* W = (L == 0) ? W1 : (L == 1) ? W2 : W3;
        int n = 32 * mtp + (lane & 31);
        int hh2 = lane >> 5;
        #pragma unroll
        for (int i = 0; i < 8; ++i) {
            int k = 16 * s + 8 * hh2 + i;
            unsigned short hh, ll;
            bf16split(W[n * 64 + k], hh, ll);
            ws[idx * 8 + i] = hh;
            ws[12288 + idx * 8 + i] = ll;
        }
    } else if (idx < 1664) {
        int j = idx - 1536;
        int mtp = j >> 6, lane = j & 63;
        int n = 32 * mtp + (lane & 31);
        int hh2 = lane >> 5;
        #pragma unroll
        for (int i = 0; i < 8; ++i) {
            int k = 8 * hh2 + i;
            float v = (k < 3) ? W0[n * 3 + k] : ((k == 3) ? b0[n] : 0.0f);
            unsigned short hh, ll;
            bf16split(v, hh, ll);
            ws[24576 + j * 8 + i] = hh;
            ws[25600 + j * 8 + i] = ll;
        }
    }
}

// Build next-layer B-fragments from packed D-values via v_permlane32_swap.
#define BUILD_FRAGS(fr)                                               \
    BFr fr[4][2];                                                     \
    _Pragma("unroll")                                                 \
    for (int nt = 0; nt < 2; ++nt) {                                  \
        _Pragma("unroll")                                             \
        for (int s = 0; s < 4; ++s) {                                 \
            const int mt = s >> 1, e = 4 * (s & 1);                   \
            unsigned x1 = pk[mt][nt][e + 0], y1 = pk[mt][nt][e + 2];  \
            unsigned x2 = pk[mt][nt][e + 1], y2 = pk[mt][nt][e + 3];  \
            asm("v_permlane32_swap_b32 %0, %1" : "+v"(x1), "+v"(y1)); \
            asm("v_permlane32_swap_b32 %0, %1" : "+v"(x2), "+v"(y2)); \
            fr[s][nt].u = (u32x4){x1, x2, y1, y2};                    \
        }                                                             \
    }

__global__ __launch_bounds__(NPB, 4)
void bgk_mfma(const float* __restrict__ f,
              const float* __restrict__ macro,
              const float* __restrict__ pos,
              const float* __restrict__ b1,
              const float* __restrict__ b2,
              const float* __restrict__ b3,
              const float* __restrict__ W4,
              const float* __restrict__ b4,
              const unsigned short* __restrict__ ws,
              float* __restrict__ out, int n_nodes)
{
    __shared__ float4 s_prm[NPB];   // per-node {1/tau, lam, mu0, r}

    const int lane = threadIdx.x & 63;
    const int c5 = lane & 31, h = lane >> 5;
    const int nbase = blockIdx.x * NPB;
    const float XI_H = 70.0f / 63.0f;

    // ---- T14: issue phase-2 batch-0 f-loads NOW; HBM latency hides under MLP ----
    const int sub = lane >> 4;
    const int qi = (lane & 15) * 4;
    float4 pre[8];
    #pragma unroll
    for (int k = 0; k < 8; ++k) {
        int n = nbase + k * 4 + sub;
        int ncl = (n < n_nodes) ? n : (n_nodes - 1);
        pre[k] = *(const float4*)(f + (size_t)ncl * Q + qi);
    }

    // ---- prolog: analytic lambda/mu0/r per node (lane t <-> node nbase+t) ----
    float lam, mu0, rgeo;
    {
        int n1 = nbase + lane;
        int nc2 = (n1 < n_nodes) ? n1 : (n_nodes - 1);
        float m0 = macro[nc2 * 2];
        rgeo = fmaxf(m0 / (m0 + XI_H), 1e-30f);
        float lr = logf(rgeo);
        lam = lr / XI_H;
        float r64 = __expf(64.0f * lr);
        mu0 = -logf((1.0f - r64) / (1.0f - rgeo));
    }

    const bf16x8* wAh = (const bf16x8*)(ws);
    const bf16x8* wAl = (const bf16x8*)(ws + 12288);
    const bf16x8* l0h = (const bf16x8*)(ws + 24576);
    const bf16x8* l0l = (const bf16x8*)(ws + 25600);
    const f32x16 zero16 = {0,0,0,0,0,0,0,0,0,0,0,0,0,0,0,0};

    unsigned pk[2][2][8];

    // ---- layer 0 (3->64), K=16, bias folded as input row k=3 of 1.0 ----
    {
        BFr bh[2], bl[2];
        #pragma unroll
        for (int nt = 0; nt < 2; ++nt) {
            int node = nbase + 32 * nt + c5;
            if (node >= n_nodes) node = n_nodes - 1;
            float m0 = macro[node * 2], m1 = macro[node * 2 + 1], pp = pos[node];
            unsigned short h0, l0_, h1, l1_, h2, l2_;
            bf16split(m0, h0, l0_); bf16split(m1, h1, l1_); bf16split(pp, h2, l2_);
            unsigned w0h = (unsigned)h0 | ((unsigned)h1 << 16);
            unsigned w1h = (unsigned)h2 | (0x3F80u << 16);
            unsigned w0l = (unsigned)l0_ | ((unsigned)l1_ << 16);
            unsigned w1l = (unsigned)l2_;
            bh[nt].u = (u32x4){ h ? 0u : w0h, h ? 0u : w1h, 0u, 0u };
            bl[nt].u = (u32x4){ h ? 0u : w0l, h ? 0u : w1l, 0u, 0u };
        }
        #pragma unroll
        for (int mtp = 0; mtp < 2; ++mtp) {
            bf16x8 Ah = l0h[mtp * 64 + lane];
            bf16x8 Al = l0l[mtp * 64 + lane];
            #pragma unroll
            for (int nt = 0; nt < 2; ++nt) {
                f32x16 t = zero16;
                t = MFMA32(Ah, bh[nt].v, t);
                t = MFMA32(Al, bh[nt].v, t);
                t = MFMA32(Ah, bl[nt].v, t);
                #pragma unroll
                for (int p = 0; p < 8; ++p) {
                    float y0, y1;
                    pade_tanh2(t[2 * p], t[2 * p + 1], y0, y1);
                    pk[mtp][nt][p] = cvt_pk_bf16(y0, y1);
                }
            }
        }
    }

    // ---- hidden layers 1,2 (64->64): bias folded into MFMA C-init ----
#define HIDDEN(Lc, BIAS)                                                       \
    {                                                                          \
        BUILD_FRAGS(fr)                                                        \
        _Pragma("unroll")                                                      \
        for (int mtp = 0; mtp < 2; ++mtp) {                                    \
            f32x16 a0;                                                         \
            _Pragma("unroll")                                                  \
            for (int j = 0; j < 4; ++j) {                                      \
                float4 bv = *(const float4*)&(BIAS)[32 * mtp + 8 * j + 4 * h]; \
                a0[4 * j + 0] = bv.x; a0[4 * j + 1] = bv.y;                    \
                a0[4 * j + 2] = bv.z; a0[4 * j + 3] = bv.w;                    \
            }                                                                  \
            f32x16 a1 = a0;                                                    \
            _Pragma("unroll")                                                  \
            for (int s = 0; s < 4; ++s) {                                      \
                const int fo = (((Lc) * 2 + mtp) * 4 + s) * 64 + lane;         \
                bf16x8 Ah = wAh[fo], Al = wAl[fo];                             \
                a0 = MFMA32(Ah, fr[s][0].v, a0);                               \
                a0 = MFMA32(Al, fr[s][0].v, a0);                               \
                a1 = MFMA32(Ah, fr[s][1].v, a1);                               \
                a1 = MFMA32(Al, fr[s][1].v, a1);                               \
            }                                                                  \
            _Pragma("unroll")                                                  \
            for (int j = 0; j < 4; ++j) {                                      \
                float v0, v1, v2, v3;                                          \
                pade_tanh2(a0[4 * j + 0], a0[4 * j + 1], v0, v1);              \
                pade_tanh2(a0[4 * j + 2], a0[4 * j + 3], v2, v3);              \
                pk[mtp][0][2 * j + 0] = cvt_pk_bf16(v0, v1);                   \
                pk[mtp][0][2 * j + 1] = cvt_pk_bf16(v2, v3);                   \
                float u0, u1, u2, u3;                                          \
                pade_tanh2(a1[4 * j + 0], a1[4 * j + 1], u0, u1);              \
                pade_tanh2(a1[4 * j + 2], a1[4 * j + 3], u2, u3);              \
                pk[mtp][1][2 * j + 0] = cvt_pk_bf16(u0, u1);                   \
                pk[mtp][1][2 * j + 1] = cvt_pk_bf16(u2, u3);                   \
            }                                                                  \
        }                                                                      \
    }

    HIDDEN(0, b1)
    HIDDEN(1, b2)

    // ---- layer 3 + head (64->64->1): bias folded into C-init, fold W4 ----
    {
        BUILD_FRAGS(fr)
        float zp0 = 0.f, zp1 = 0.f;
        #pragma unroll
        for (int mtp = 0; mtp < 2; ++mtp) {
            f32x16 a0;
            #pragma unroll
            for (int j = 0; j < 4; ++j) {
                float4 bv = *(const float4*)&b3[32 * mtp + 8 * j + 4 * h];
                a0[4 * j + 0] = bv.x; a0[4 * j + 1] = bv.y;
                a0[4 * j + 2] = bv.z; a0[4 * j + 3] = bv.w;
            }
            f32x16 a1 = a0;
            #pragma unroll
            for (int s = 0; s < 4; ++s) {
                const int fo = ((2 * 2 + mtp) * 4 + s) * 64 + lane;
                bf16x8 Ah = wAh[fo], Al = wAl[fo];
                a0 = MFMA32(Ah, fr[s][0].v, a0);
                a0 = MFMA32(Al, fr[s][0].v, a0);
                a1 = MFMA32(Ah, fr[s][1].v, a1);
                a1 = MFMA32(Al, fr[s][1].v, a1);
            }
            #pragma unroll
            for (int j = 0; j < 4; ++j) {
                float4 w4v = *(const float4*)&W4[32 * mtp + 8 * j + 4 * h];
                float s0, s1, s2, s3;
                pade_tanh2(a0[4 * j + 0], a0[4 * j + 1], s0, s1);
                pade_tanh2(a0[4 * j + 2], a0[4 * j + 3], s2, s3);
                zp0 = fmaf(w4v.x, s0, zp0);
                zp0 = fmaf(w4v.y, s1, zp0);
                zp0 = fmaf(w4v.z, s2, zp0);
                zp0 = fmaf(w4v.w, s3, zp0);
                float r0, r1, r2, r3;
                pade_tanh2(a1[4 * j + 0], a1[4 * j + 1], r0, r1);
                pade_tanh2(a1[4 * j + 2], a1[4 * j + 3], r2, r3);
                zp1 = fmaf(w4v.x, r0, zp1);
                zp1 = fmaf(w4v.y, r1, zp1);
                zp1 = fmaf(w4v.z, r2, zp1);
                zp1 = fmaf(w4v.w, r3, zp1);
            }
        }
        const float b4s = b4[0];
        zp0 += __shfl_xor(zp0, 32, 64);
        zp1 += __shfl_xor(zp1, 32, 64);
        float it0 = __expf(-(zp0 + b4s));
        float it1 = __expf(-(zp1 + b4s));
        float it  = h ? it1 : it0;
        s_prm[lane] = (float4){ it, lam, mu0, rgeo };
    }

    // ---- Phase 2: batch 0 preloaded; DPP reduce; 1 ds_read_b128 for params ----
    const float x0 = (float)qi * XI_H;
    {
        float4 fr2[8];
        #pragma unroll
        for (int k = 0; k < 8; ++k) {
            int n = nbase + (8 + k) * 4 + sub;
            int ncl = (n < n_nodes) ? n : (n_nodes - 1);
            fr2[k] = *(const float4*)(f + (size_t)ncl * Q + qi);
        }
        #pragma unroll
        for (int kb = 0; kb < 2; ++kb) {
            #pragma unroll
            for (int k = 0; k < 8; ++k) {
                const int local = (kb * 8 + k) * 4 + sub;
                const int n = nbase + local;
                const float4 fv = kb ? fr2[k] : pre[k];

                const float s = sum16_dpp(fv.x + fv.y + fv.z + fv.w);
                const float rho = s * (1.0f / 64.0f);

                const float4 prm = s_prm[local];   // {it, lam, mu0, r}

                const float e0 = rho * __expf(fmaf(prm.y, x0, prm.z));
                const float e1 = e0 * prm.w;
                const float e2 = e1 * prm.w;
                const float e3 = e2 * prm.w;

                float4 o;
                o.x = (e0 - fv.x) * prm.x;
                o.y = (e1 - fv.y) * prm.x;
                o.z = (e2 - fv.z) * prm.x;
                o.w = (e3 - fv.w) * prm.x;

                if (n < n_nodes) *(float4*)(out + (size_t)n * Q + qi) = o;
            }
        }
    }
}

extern "C" void kernel_launch(void* const* d_in, const int* in_sizes, int n_in,
                              void* d_out, int out_size, void* d_ws, size_t ws_size,
                              hipStream_t stream) {
    const float* f     = (const float*)d_in[0];
    const float* macro = (const float*)d_in[1];
    const float* pos   = (const float*)d_in[2];
    const float* W0 = (const float*)d_in[3];  const float* b0 = (const float*)d_in[4];
    const float* W1 = (const float*)d_in[5];  const float* b1 = (const float*)d_in[6];
    const float* W2 = (const float*)d_in[7];  const float* b2 = (const float*)d_in[8];
    const float* W3 = (const float*)d_in[9];  const float* b3 = (const float*)d_in[10];
    const float* W4 = (const float*)d_in[11]; const float* b4 = (const float*)d_in[12];
    float* out = (float*)d_out;
    unsigned short* ws = (unsigned short*)d_ws;   // 53,248 B used

    const int n_nodes = in_sizes[0] / Q;   // 500000
    build_wfrag<<<7, 256, 0, stream>>>(W0, b0, W1, W2, W3, ws);

    const int blocks = (n_nodes + NPB - 1) / NPB;
    bgk_mfma<<<blocks, NPB, 0, stream>>>(f, macro, pos,
                                         b1, b2, b3, W4, b4, ws,
                                         out, n_nodes);
}